// Round 1
// baseline (1641.202 us; speedup 1.0000x reference)
//
#include <hip/hip_runtime.h>
#include <math.h>

// Problem dims (fixed)
#define BATCH 4
#define CQ 256      // x channels
#define P 4096      // query positions (64*64)
#define CC 512      // context channels
#define PC 1024     // kv positions (32*32)
#define HID 512     // HEADS*DIM_HEAD
#define HEADS 8
#define DH 64

// ---------------------------------------------------------------------------
// Generic fp32 tiled GEMM: C[b] = A (MxK, shared over batch) * B[b] (KxN) + bias
// 64x64 tile, BK=16, 256 threads, 4x4 micro-tile per thread.
// ---------------------------------------------------------------------------
#define BK 16
__global__ __launch_bounds__(256) void gemm_f32(
    const float* __restrict__ A, const float* __restrict__ B,
    float* __restrict__ C, const float* __restrict__ bias,
    int M, int K, int N)
{
    const int b = blockIdx.z;
    const float* Bb = B + (size_t)b * K * N;
    float* Cb = C + (size_t)b * M * N;
    const int tn = blockIdx.x * 64;
    const int tm = blockIdx.y * 64;
    const int tid = threadIdx.x;
    const int tx = tid & 15, ty = tid >> 4;

    __shared__ float As[BK][64 + 4];  // [kk][m] (transposed on load)
    __shared__ float Bs[BK][64 + 4];  // [kk][n]

    float acc[4][4] = {};

    for (int k0 = 0; k0 < K; k0 += BK) {
        {   // A tile: each thread loads float4 along k, scatters transposed
            int m = tid >> 2;            // 0..63
            int kk = (tid & 3) * 4;      // 0,4,8,12
            const float4 a4 = *reinterpret_cast<const float4*>(
                &A[(size_t)(tm + m) * K + k0 + kk]);
            As[kk + 0][m] = a4.x;
            As[kk + 1][m] = a4.y;
            As[kk + 2][m] = a4.z;
            As[kk + 3][m] = a4.w;
        }
        {   // B tile: coalesced float4 along n
            int kk = tid >> 4;           // 0..15
            int n = (tid & 15) * 4;
            *reinterpret_cast<float4*>(&Bs[kk][n]) =
                *reinterpret_cast<const float4*>(
                    &Bb[(size_t)(k0 + kk) * N + tn + n]);
        }
        __syncthreads();
        #pragma unroll
        for (int kk = 0; kk < BK; ++kk) {
            float4 a = *reinterpret_cast<const float4*>(&As[kk][ty * 4]);
            float4 bv = *reinterpret_cast<const float4*>(&Bs[kk][tx * 4]);
            float av[4] = {a.x, a.y, a.z, a.w};
            float bb[4] = {bv.x, bv.y, bv.z, bv.w};
            #pragma unroll
            for (int i2 = 0; i2 < 4; ++i2)
                #pragma unroll
                for (int j2 = 0; j2 < 4; ++j2)
                    acc[i2][j2] = fmaf(av[i2], bb[j2], acc[i2][j2]);
        }
        __syncthreads();
    }
    #pragma unroll
    for (int i2 = 0; i2 < 4; ++i2) {
        int m = tm + ty * 4 + i2;
        float bval = bias ? bias[m] : 0.f;
        float4 o4 = make_float4(acc[i2][0] + bval, acc[i2][1] + bval,
                                acc[i2][2] + bval, acc[i2][3] + bval);
        *reinterpret_cast<float4*>(&Cb[(size_t)m * N + tn + tx * 4]) = o4;
    }
}

// ---------------------------------------------------------------------------
// Flash-style fused attention (fp32). One block = one (b, h, 64-query tile).
// q,k stored [c][pos]; online softmax over 16 kv-tiles of 64.
// kp_s doubles as K tile (S phase) and P^T tile (PV phase) to fit LDS.
// ---------------------------------------------------------------------------
__global__ __launch_bounds__(256) void attn_f32(
    const float* __restrict__ q,  // [B, 512, 4096]
    const float* __restrict__ k,  // [B, 512, 1024]
    const float* __restrict__ v,  // [B, 512, 1024]
    float* __restrict__ o)        // [B, 512, 4096]
{
    const int it = blockIdx.x;     // query tile
    const int h = blockIdx.y;
    const int b = blockIdx.z;
    const int tid = threadIdx.x;
    const int tx = tid & 15, ty = tid >> 4;

    const size_t qbase = ((size_t)b * HID + h * DH) * P + (size_t)it * 64;
    const size_t kbase = ((size_t)b * HID + h * DH) * PC;

    __shared__ float q_s[64][68];   // [c][i]
    __shared__ float kp_s[64][68];  // K: [c][j]  then  P^T: [j][i]
    __shared__ float v_s[64][68];   // [j][c] (transposed on load)
    __shared__ float fac_s[64];
    __shared__ float l_s[64];

    #pragma unroll
    for (int itr = 0; itr < 4; ++itr) {
        int c = (tid >> 4) + itr * 16;
        int i = (tid & 15) * 4;
        *reinterpret_cast<float4*>(&q_s[c][i]) =
            *reinterpret_cast<const float4*>(&q[qbase + (size_t)c * P + i]);
    }

    float o_acc[4][4] = {};          // [cc][ii2]: c=ty*4+cc, i=tx*4+ii2
    float m_reg[4], l_reg[4];
    #pragma unroll
    for (int i2 = 0; i2 < 4; ++i2) { m_reg[i2] = -1e30f; l_reg[i2] = 0.f; }

    for (int jt = 0; jt < 16; ++jt) {
        __syncthreads();  // previous PV done with kp_s / v_s
        #pragma unroll
        for (int itr = 0; itr < 4; ++itr) {
            int c = (tid >> 4) + itr * 16;
            int j0 = (tid & 15) * 4;
            const size_t g = kbase + (size_t)c * PC + jt * 64 + j0;
            *reinterpret_cast<float4*>(&kp_s[c][j0]) =
                *reinterpret_cast<const float4*>(&k[g]);
            float4 v4 = *reinterpret_cast<const float4*>(&v[g]);
            v_s[j0 + 0][c] = v4.x; v_s[j0 + 1][c] = v4.y;
            v_s[j0 + 2][c] = v4.z; v_s[j0 + 3][c] = v4.w;
        }
        __syncthreads();

        // S[i][j], i = ty*4+ii, j = tx*4+jj
        float s[4][4] = {};
        #pragma unroll
        for (int c = 0; c < 64; ++c) {
            float4 qa = *reinterpret_cast<const float4*>(&q_s[c][ty * 4]);
            float4 ka = *reinterpret_cast<const float4*>(&kp_s[c][tx * 4]);
            float qv[4] = {qa.x, qa.y, qa.z, qa.w};
            float kv[4] = {ka.x, ka.y, ka.z, ka.w};
            #pragma unroll
            for (int ii = 0; ii < 4; ++ii)
                #pragma unroll
                for (int jj = 0; jj < 4; ++jj)
                    s[ii][jj] = fmaf(qv[ii], kv[jj], s[ii][jj]);
        }
        // online softmax (row = i, reduce across tx lanes: 16-lane groups)
        #pragma unroll
        for (int ii = 0; ii < 4; ++ii) {
            float rm = -1e30f;
            #pragma unroll
            for (int jj = 0; jj < 4; ++jj) {
                s[ii][jj] *= 0.125f;
                rm = fmaxf(rm, s[ii][jj]);
            }
            #pragma unroll
            for (int msk = 1; msk < 16; msk <<= 1)
                rm = fmaxf(rm, __shfl_xor(rm, msk, 64));
            float m_new = fmaxf(m_reg[ii], rm);
            float fac = __expf(m_reg[ii] - m_new);
            float rs = 0.f;
            #pragma unroll
            for (int jj = 0; jj < 4; ++jj) {
                float p = __expf(s[ii][jj] - m_new);
                s[ii][jj] = p;
                rs += p;
            }
            #pragma unroll
            for (int msk = 1; msk < 16; msk <<= 1)
                rs += __shfl_xor(rs, msk, 64);
            l_reg[ii] = l_reg[ii] * fac + rs;
            m_reg[ii] = m_new;
            if (tx == 0) fac_s[ty * 4 + ii] = fac;
        }
        __syncthreads();  // all S reads of kp_s (as K) done
        #pragma unroll
        for (int ii = 0; ii < 4; ++ii)
            #pragma unroll
            for (int jj = 0; jj < 4; ++jj)
                kp_s[tx * 4 + jj][ty * 4 + ii] = s[ii][jj];  // P^T: [j][i]
        __syncthreads();  // P + fac visible

        #pragma unroll
        for (int ii2 = 0; ii2 < 4; ++ii2) {
            float f = fac_s[tx * 4 + ii2];
            #pragma unroll
            for (int cc = 0; cc < 4; ++cc) o_acc[cc][ii2] *= f;
        }
        #pragma unroll
        for (int j = 0; j < 64; ++j) {
            float4 vv = *reinterpret_cast<const float4*>(&v_s[j][ty * 4]);
            float4 pp = *reinterpret_cast<const float4*>(&kp_s[j][tx * 4]);
            float va[4] = {vv.x, vv.y, vv.z, vv.w};
            float pa[4] = {pp.x, pp.y, pp.z, pp.w};
            #pragma unroll
            for (int cc = 0; cc < 4; ++cc)
                #pragma unroll
                for (int ii2 = 0; ii2 < 4; ++ii2)
                    o_acc[cc][ii2] = fmaf(va[cc], pa[ii2], o_acc[cc][ii2]);
        }
    }

    if (tx == 0) {
        #pragma unroll
        for (int ii = 0; ii < 4; ++ii) l_s[ty * 4 + ii] = l_reg[ii];
    }
    __syncthreads();
    #pragma unroll
    for (int cc = 0; cc < 4; ++cc) {
        int ch = ty * 4 + cc;
        float4 o4;
        o4.x = o_acc[cc][0] / l_s[tx * 4 + 0];
        o4.y = o_acc[cc][1] / l_s[tx * 4 + 1];
        o4.z = o_acc[cc][2] / l_s[tx * 4 + 2];
        o4.w = o_acc[cc][3] / l_s[tx * 4 + 3];
        *reinterpret_cast<float4*>(&o[qbase + (size_t)ch * P + tx * 4]) = o4;
    }
}

extern "C" void kernel_launch(void* const* d_in, const int* in_sizes, int n_in,
                              void* d_out, int out_size, void* d_ws, size_t ws_size,
                              hipStream_t stream) {
    (void)in_sizes; (void)n_in; (void)out_size; (void)ws_size;
    const float* x   = (const float*)d_in[0];
    const float* ctx = (const float*)d_in[1];
    const float* Wq  = (const float*)d_in[2];
    const float* Wk  = (const float*)d_in[3];
    const float* Wv  = (const float*)d_in[4];
    const float* Wo  = (const float*)d_in[5];
    const float* bo  = (const float*)d_in[6];
    float* out = (float*)d_out;

    float* ws = (float*)d_ws;
    float* q_ws = ws;                       // 4*512*4096 = 8388608 f
    float* k_ws = q_ws + (size_t)BATCH * HID * P;    // 4*512*1024
    float* v_ws = k_ws + (size_t)BATCH * HID * PC;
    float* o_ws = v_ws + (size_t)BATCH * HID * PC;   // 4*512*4096

    dim3 blk(256);
    // K = Wk @ ctx, V = Wv @ ctx   (M=512, K=512, N=1024)
    gemm_f32<<<dim3(PC / 64, HID / 64, BATCH), blk, 0, stream>>>(
        Wk, ctx, k_ws, nullptr, HID, CC, PC);
    gemm_f32<<<dim3(PC / 64, HID / 64, BATCH), blk, 0, stream>>>(
        Wv, ctx, v_ws, nullptr, HID, CC, PC);
    // Q = Wq @ x                    (M=512, K=256, N=4096)
    gemm_f32<<<dim3(P / 64, HID / 64, BATCH), blk, 0, stream>>>(
        Wq, x, q_ws, nullptr, HID, CQ, P);
    // fused attention
    attn_f32<<<dim3(P / 64, HEADS, BATCH), blk, 0, stream>>>(
        q_ws, k_ws, v_ws, o_ws);
    // out = Wo @ o + bo             (M=256, K=512, N=4096)
    gemm_f32<<<dim3(P / 64, CQ / 64, BATCH), blk, 0, stream>>>(
        Wo, o_ws, out, bo, CQ, HID, P);
}

// Round 2
// 432.697 us; speedup vs baseline: 3.7930x; 3.7930x over previous
//
#include <hip/hip_runtime.h>
#include <math.h>
#include <stdint.h>

// Problem dims (fixed)
#define BATCH 4
#define CQ 256      // x channels
#define P 4096      // query positions (64*64)
#define CC 512      // context channels
#define PC 1024     // kv positions (32*32)
#define HID 512     // HEADS*DIM_HEAD
#define HEADS 8
#define DH 64

// Fold attention scale 1/sqrt(64) * log2(e) into Q so softmax uses exp2.
#define QSCALE 0.180336880111113703f

typedef __attribute__((ext_vector_type(8))) short bf16x8;
typedef __attribute__((ext_vector_type(4))) float f32x4;

union FragU { uint32_t u[4]; bf16x8 v; };

__device__ __forceinline__ uint32_t pk2(float a, float b) {
    // pack two fp32 as truncated bf16: a -> low 16, b -> high 16
    return (__float_as_uint(a) >> 16) | (__float_as_uint(b) & 0xffff0000u);
}
__device__ __forceinline__ float hif(float a) {
    // the fp32 value of trunc-bf16(a)
    return __uint_as_float(__float_as_uint(a) & 0xffff0000u);
}

#define MFMA16(a, b, c) __builtin_amdgcn_mfma_f32_16x16x32_bf16(a, b, c, 0, 0, 0)

// ---------------------------------------------------------------------------
// fp32 tiled GEMM: C[b] = A (MxK, shared) * B[b] (KxN); epilogue writes
// split bf16 hi/lo. MODE 0: out[b][h][pos][c64] (Q/K, pos-major per head);
// MODE 1: out[b][chan][pos] (V, channel-major).
// ---------------------------------------------------------------------------
template<int MODE>
__global__ __launch_bounds__(256) void gemm_split(
    const float* __restrict__ A, const float* __restrict__ B,
    unsigned short* __restrict__ Dh, unsigned short* __restrict__ Dl,
    float scale, int M, int K, int N)
{
    const int b = blockIdx.z;
    const float* Bb = B + (size_t)b * K * N;
    const int tn = blockIdx.x * 64;
    const int tm = blockIdx.y * 64;
    const int tid = threadIdx.x;
    const int tx = tid & 15, ty = tid >> 4;

    __shared__ float As[16][68];  // [kk][m]
    __shared__ float Bs[16][68];  // [kk][n]

    float acc[4][4] = {};

    for (int k0 = 0; k0 < K; k0 += 16) {
        {
            int m = tid >> 2;
            int kk = (tid & 3) * 4;
            const float4 a4 = *reinterpret_cast<const float4*>(
                &A[(size_t)(tm + m) * K + k0 + kk]);
            As[kk + 0][m] = a4.x; As[kk + 1][m] = a4.y;
            As[kk + 2][m] = a4.z; As[kk + 3][m] = a4.w;
        }
        {
            int kk = tid >> 4;
            int n = (tid & 15) * 4;
            *reinterpret_cast<float4*>(&Bs[kk][n]) =
                *reinterpret_cast<const float4*>(&Bb[(size_t)(k0 + kk) * N + tn + n]);
        }
        __syncthreads();
        #pragma unroll
        for (int kk = 0; kk < 16; ++kk) {
            float4 a = *reinterpret_cast<const float4*>(&As[kk][ty * 4]);
            float4 bv = *reinterpret_cast<const float4*>(&Bs[kk][tx * 4]);
            float av[4] = {a.x, a.y, a.z, a.w};
            float bb[4] = {bv.x, bv.y, bv.z, bv.w};
            #pragma unroll
            for (int i2 = 0; i2 < 4; ++i2)
                #pragma unroll
                for (int j2 = 0; j2 < 4; ++j2)
                    acc[i2][j2] = fmaf(av[i2], bb[j2], acc[i2][j2]);
        }
        __syncthreads();
    }

    if (MODE == 0) {
        const int h = tm >> 6;  // tile spans exactly one head (tm % 64 == 0)
        #pragma unroll
        for (int j2 = 0; j2 < 4; ++j2) {
            int pos = tn + tx * 4 + j2;
            float v0 = scale * acc[0][j2], v1 = scale * acc[1][j2];
            float v2 = scale * acc[2][j2], v3 = scale * acc[3][j2];
            uint32_t hw0 = pk2(v0, v1), hw1 = pk2(v2, v3);
            float r0 = v0 - hif(v0), r1 = v1 - hif(v1);
            float r2 = v2 - hif(v2), r3 = v3 - hif(v3);
            uint32_t lw0 = pk2(r0, r1), lw1 = pk2(r2, r3);
            size_t off = (((size_t)b * HEADS + h) * (size_t)N + pos) * 64 + ty * 4;
            uint2 hh; hh.x = hw0; hh.y = hw1;
            uint2 ll; ll.x = lw0; ll.y = lw1;
            *reinterpret_cast<uint2*>(Dh + off) = hh;
            *reinterpret_cast<uint2*>(Dl + off) = ll;
        }
    } else {
        #pragma unroll
        for (int i2 = 0; i2 < 4; ++i2) {
            int c = tm + ty * 4 + i2;
            float v0 = acc[i2][0], v1 = acc[i2][1];
            float v2 = acc[i2][2], v3 = acc[i2][3];
            uint32_t hw0 = pk2(v0, v1), hw1 = pk2(v2, v3);
            float r0 = v0 - hif(v0), r1 = v1 - hif(v1);
            float r2 = v2 - hif(v2), r3 = v3 - hif(v3);
            uint32_t lw0 = pk2(r0, r1), lw1 = pk2(r2, r3);
            size_t off = ((size_t)b * HID + c) * (size_t)N + tn + tx * 4;
            uint2 hh; hh.x = hw0; hh.y = hw1;
            uint2 ll; ll.x = lw0; ll.y = lw1;
            *reinterpret_cast<uint2*>(Dh + off) = hh;
            *reinterpret_cast<uint2*>(Dl + off) = ll;
        }
    }
}

// ---------------------------------------------------------------------------
// Split a small fp32 weight into bf16 hi/lo (for Wo).
// ---------------------------------------------------------------------------
__global__ __launch_bounds__(256) void split_w(
    const float* __restrict__ W,
    unsigned short* __restrict__ Hh, unsigned short* __restrict__ Hl, int n)
{
    int i = blockIdx.x * 256 + threadIdx.x;
    if (i < n) {
        float f = W[i];
        Hh[i] = (unsigned short)(__float_as_uint(f) >> 16);
        float r = f - hif(f);
        Hl[i] = (unsigned short)(__float_as_uint(r) >> 16);
    }
}

// ---------------------------------------------------------------------------
// Register-resident flash attention, split-bf16 MFMA, 1 wave / 64 queries.
// Swapped matmuls: S^T = mfma(K,Q), O^T = mfma(V,P) so softmax state lives
// at lane&15 (the D-frag column) and no cross-lane transpose of m/l/fac is
// needed. P is redistributed from S^T D-frags to PV B-frags with 8 shfls.
//   q layout: [b][h][i][64c] bf16 hi/lo (Q pre-scaled by QSCALE)
//   k layout: [b][h][j][64c] bf16 hi/lo
//   v layout: [b][c_full][j] bf16 hi/lo
//   o layout: [b][i][c_full] fp32
// ---------------------------------------------------------------------------
__global__ __launch_bounds__(64) void attn_mfma(
    const unsigned short* __restrict__ qh, const unsigned short* __restrict__ ql,
    const unsigned short* __restrict__ kh, const unsigned short* __restrict__ kl,
    const unsigned short* __restrict__ vh, const unsigned short* __restrict__ vl,
    float* __restrict__ o)
{
    const int i0 = blockIdx.x * 64;
    const int h = blockIdx.y, b = blockIdx.z;
    const int l = threadIdx.x;
    const int ln = l & 15, g = l >> 4;

    const size_t qbase = (size_t)(b * HEADS + h) * P * 64;
    const size_t kbase = (size_t)(b * HEADS + h) * PC * 64;
    const size_t vbase = (size_t)(b * HID + h * DH) * PC;

    // Q B-frags: lane holds q_t[i = i0+16*in+ln][c = 32*ks+8*g .. +7]
    bf16x8 qf[4][2][2];
    #pragma unroll
    for (int in_ = 0; in_ < 4; ++in_) {
        int i = i0 + 16 * in_ + ln;
        #pragma unroll
        for (int ks = 0; ks < 2; ++ks) {
            size_t off = qbase + (size_t)i * 64 + 32 * ks + 8 * g;
            qf[in_][ks][0] = *reinterpret_cast<const bf16x8*>(qh + off);
            qf[in_][ks][1] = *reinterpret_cast<const bf16x8*>(ql + off);
        }
    }

    f32x4 acc[4][4];  // O^T frags: [c_m][i_n]; rows c=16cm+4g+r, col i=16in+ln
    #pragma unroll
    for (int cm = 0; cm < 4; ++cm)
        #pragma unroll
        for (int in_ = 0; in_ < 4; ++in_) {
            f32x4 z = {0.f, 0.f, 0.f, 0.f};
            acc[cm][in_] = z;
        }
    float mst[4], lst[4];
    #pragma unroll
    for (int in_ = 0; in_ < 4; ++in_) { mst[in_] = -1e30f; lst[in_] = 0.f; }

    const int idx0 = ln + 16 * (2 * (g & 1));
    const int idx1 = idx0 + 16;
    const bool topTile = (g & 2) != 0;

    for (int jt = 0; jt < PC / 32; ++jt) {
        const int j0 = jt * 32;

        // ---- S^T = K * Q (3-term split) ----
        f32x4 s[2][4];
        #pragma unroll
        for (int jm = 0; jm < 2; ++jm)
            #pragma unroll
            for (int in_ = 0; in_ < 4; ++in_) {
                f32x4 z = {0.f, 0.f, 0.f, 0.f};
                s[jm][in_] = z;
            }
        #pragma unroll
        for (int jm = 0; jm < 2; ++jm) {
            const size_t krow = kbase + (size_t)(j0 + 16 * jm + ln) * 64;
            #pragma unroll
            for (int ks = 0; ks < 2; ++ks) {
                bf16x8 kfh = *reinterpret_cast<const bf16x8*>(kh + krow + 32 * ks + 8 * g);
                bf16x8 kfl = *reinterpret_cast<const bf16x8*>(kl + krow + 32 * ks + 8 * g);
                #pragma unroll
                for (int in_ = 0; in_ < 4; ++in_) {
                    s[jm][in_] = MFMA16(kfh, qf[in_][ks][0], s[jm][in_]);
                    s[jm][in_] = MFMA16(kfh, qf[in_][ks][1], s[jm][in_]);
                    s[jm][in_] = MFMA16(kfl, qf[in_][ks][0], s[jm][in_]);
                }
            }
        }

        // ---- online softmax over j (rows of S^T); per-lane i = ln ----
        uint32_t pw[2][4][2][2];  // [jm][in][hi/lo][word]
        #pragma unroll
        for (int in_ = 0; in_ < 4; ++in_) {
            float tmx = fmaxf(fmaxf(fmaxf(s[0][in_][0], s[0][in_][1]),
                                    fmaxf(s[0][in_][2], s[0][in_][3])),
                              fmaxf(fmaxf(s[1][in_][0], s[1][in_][1]),
                                    fmaxf(s[1][in_][2], s[1][in_][3])));
            tmx = fmaxf(tmx, __shfl_xor(tmx, 16, 64));
            tmx = fmaxf(tmx, __shfl_xor(tmx, 32, 64));
            float mnew = fmaxf(mst[in_], tmx);
            float fac = exp2f(mst[in_] - mnew);
            float rs = 0.f;
            #pragma unroll
            for (int jm = 0; jm < 2; ++jm)
                #pragma unroll
                for (int r = 0; r < 4; ++r) {
                    float p = exp2f(s[jm][in_][r] - mnew);
                    s[jm][in_][r] = p;
                    rs += p;
                }
            rs += __shfl_xor(rs, 16, 64);
            rs += __shfl_xor(rs, 32, 64);
            lst[in_] = lst[in_] * fac + rs;
            mst[in_] = mnew;
            // pack P to bf16 hi/lo words (word0: rows r0,r1; word1: r2,r3)
            #pragma unroll
            for (int jm = 0; jm < 2; ++jm) {
                float p0 = s[jm][in_][0], p1 = s[jm][in_][1];
                float p2 = s[jm][in_][2], p3 = s[jm][in_][3];
                pw[jm][in_][0][0] = pk2(p0, p1);
                pw[jm][in_][0][1] = pk2(p2, p3);
                float r0 = p0 - hif(p0), r1 = p1 - hif(p1);
                float r2 = p2 - hif(p2), r3 = p3 - hif(p3);
                pw[jm][in_][1][0] = pk2(r0, r1);
                pw[jm][in_][1][1] = pk2(r2, r3);
            }
            // rescale O^T
            #pragma unroll
            for (int cm = 0; cm < 4; ++cm)
                acc[cm][in_] *= fac;
        }

        // ---- V A-frags ----
        bf16x8 vfh[4], vfl[4];
        #pragma unroll
        for (int cm = 0; cm < 4; ++cm) {
            size_t vrow = vbase + (size_t)(16 * cm + ln) * PC + j0 + 8 * g;
            vfh[cm] = *reinterpret_cast<const bf16x8*>(vh + vrow);
            vfl[cm] = *reinterpret_cast<const bf16x8*>(vl + vrow);
        }

        // ---- P redistribution + O^T += V * P ----
        #pragma unroll
        for (int in_ = 0; in_ < 4; ++in_) {
            bf16x8 pfc[2];
            #pragma unroll
            for (int comp = 0; comp < 2; ++comp) {
                int w00 = (int)pw[0][in_][comp][0], w01 = (int)pw[0][in_][comp][1];
                int w10 = (int)pw[1][in_][comp][0], w11 = (int)pw[1][in_][comp][1];
                int a0 = __shfl(w00, idx0, 64), a1 = __shfl(w01, idx0, 64);
                int a2 = __shfl(w00, idx1, 64), a3 = __shfl(w01, idx1, 64);
                int b0 = __shfl(w10, idx0, 64), b1 = __shfl(w11, idx0, 64);
                int b2 = __shfl(w10, idx1, 64), b3 = __shfl(w11, idx1, 64);
                FragU fu;
                fu.u[0] = (uint32_t)(topTile ? b0 : a0);
                fu.u[1] = (uint32_t)(topTile ? b1 : a1);
                fu.u[2] = (uint32_t)(topTile ? b2 : a2);
                fu.u[3] = (uint32_t)(topTile ? b3 : a3);
                pfc[comp] = fu.v;
            }
            #pragma unroll
            for (int cm = 0; cm < 4; ++cm) {
                acc[cm][in_] = MFMA16(vfh[cm], pfc[0], acc[cm][in_]);
                acc[cm][in_] = MFMA16(vfh[cm], pfc[1], acc[cm][in_]);
                acc[cm][in_] = MFMA16(vfl[cm], pfc[0], acc[cm][in_]);
            }
        }
    }

    // ---- epilogue: O^T / l -> o[b][i][c_full] fp32 ----
    #pragma unroll
    for (int in_ = 0; in_ < 4; ++in_) {
        float inv = 1.0f / lst[in_];
        int i = i0 + 16 * in_ + ln;
        #pragma unroll
        for (int cm = 0; cm < 4; ++cm) {
            f32x4 o4 = acc[cm][in_] * inv;
            size_t addr = ((size_t)b * P + i) * HID + h * DH + 16 * cm + 4 * g;
            *reinterpret_cast<f32x4*>(o + addr) = o4;
        }
    }
}

// ---------------------------------------------------------------------------
// Output projection: out[b][o][i] = sum_c Wo[o][c] * O[b][i][c] + bo[o].
// Split-bf16 MFMA; B (O) is fp32, split on the fly. 1 wave, BN=16, M=256.
// ---------------------------------------------------------------------------
__global__ __launch_bounds__(64) void out_proj(
    const unsigned short* __restrict__ woh, const unsigned short* __restrict__ wol,
    const float* __restrict__ ot, const float* __restrict__ bo,
    float* __restrict__ out)
{
    const int n0 = blockIdx.x * 16;
    const int b = blockIdx.z;
    const int l = threadIdx.x;
    const int ln = l & 15, g = l >> 4;

    f32x4 acc[16];
    #pragma unroll
    for (int mt = 0; mt < 16; ++mt) {
        f32x4 z = {0.f, 0.f, 0.f, 0.f};
        acc[mt] = z;
    }

    const float* brow = ot + ((size_t)b * P + n0 + ln) * HID;
    #pragma unroll
    for (int ks = 0; ks < 16; ++ks) {
        f32x4 b0 = *reinterpret_cast<const f32x4*>(brow + 32 * ks + 8 * g);
        f32x4 b1 = *reinterpret_cast<const f32x4*>(brow + 32 * ks + 8 * g + 4);
        FragU bh, bl;
        bh.u[0] = pk2(b0[0], b0[1]); bh.u[1] = pk2(b0[2], b0[3]);
        bh.u[2] = pk2(b1[0], b1[1]); bh.u[3] = pk2(b1[2], b1[3]);
        float r0 = b0[0] - hif(b0[0]), r1 = b0[1] - hif(b0[1]);
        float r2 = b0[2] - hif(b0[2]), r3 = b0[3] - hif(b0[3]);
        float r4 = b1[0] - hif(b1[0]), r5 = b1[1] - hif(b1[1]);
        float r6 = b1[2] - hif(b1[2]), r7 = b1[3] - hif(b1[3]);
        bl.u[0] = pk2(r0, r1); bl.u[1] = pk2(r2, r3);
        bl.u[2] = pk2(r4, r5); bl.u[3] = pk2(r6, r7);
        #pragma unroll
        for (int mt = 0; mt < 16; ++mt) {
            size_t aoff = (size_t)(16 * mt + ln) * HID + 32 * ks + 8 * g;
            bf16x8 ah = *reinterpret_cast<const bf16x8*>(woh + aoff);
            bf16x8 al = *reinterpret_cast<const bf16x8*>(wol + aoff);
            acc[mt] = MFMA16(ah, bh.v, acc[mt]);
            acc[mt] = MFMA16(ah, bl.v, acc[mt]);
            acc[mt] = MFMA16(al, bh.v, acc[mt]);
        }
    }

    #pragma unroll
    for (int mt = 0; mt < 16; ++mt)
        #pragma unroll
        for (int r = 0; r < 4; ++r) {
            int o_ = 16 * mt + 4 * g + r;
            out[((size_t)b * CQ + o_) * P + n0 + ln] = acc[mt][r] + bo[o_];
        }
}

extern "C" void kernel_launch(void* const* d_in, const int* in_sizes, int n_in,
                              void* d_out, int out_size, void* d_ws, size_t ws_size,
                              hipStream_t stream) {
    (void)in_sizes; (void)n_in; (void)out_size; (void)ws_size;
    const float* x   = (const float*)d_in[0];
    const float* ctx = (const float*)d_in[1];
    const float* Wq  = (const float*)d_in[2];
    const float* Wk  = (const float*)d_in[3];
    const float* Wv  = (const float*)d_in[4];
    const float* Wo  = (const float*)d_in[5];
    const float* bo  = (const float*)d_in[6];
    float* out = (float*)d_out;

    unsigned short* q_hi = (unsigned short*)d_ws;                  // 8388608
    unsigned short* q_lo = q_hi + (size_t)8388608;
    unsigned short* k_hi = q_lo + (size_t)8388608;                 // 2097152
    unsigned short* k_lo = k_hi + (size_t)2097152;
    unsigned short* v_hi = k_lo + (size_t)2097152;
    unsigned short* v_lo = v_hi + (size_t)2097152;
    float*          o_t  = (float*)(v_lo + (size_t)2097152);       // 8388608 f32
    unsigned short* wo_h = (unsigned short*)(o_t + (size_t)8388608);  // 131072
    unsigned short* wo_l = wo_h + (size_t)131072;

    dim3 blk(256);
    split_w<<<dim3(512), blk, 0, stream>>>(Wo, wo_h, wo_l, CQ * HID);
    // Q = (QSCALE * Wq) @ x   -> [b][h][pos4096][c64] hi/lo
    gemm_split<0><<<dim3(P / 64, HID / 64, BATCH), blk, 0, stream>>>(
        Wq, x, q_hi, q_lo, QSCALE, HID, CQ, P);
    // K = Wk @ ctx            -> [b][h][pos1024][c64] hi/lo
    gemm_split<0><<<dim3(PC / 64, HID / 64, BATCH), blk, 0, stream>>>(
        Wk, ctx, k_hi, k_lo, 1.0f, HID, CC, PC);
    // V = Wv @ ctx            -> [b][c512][pos1024] hi/lo
    gemm_split<1><<<dim3(PC / 64, HID / 64, BATCH), blk, 0, stream>>>(
        Wv, ctx, v_hi, v_lo, 1.0f, HID, CC, PC);
    // attention -> o_t [b][pos4096][c512] fp32
    attn_mfma<<<dim3(P / 64, HEADS, BATCH), dim3(64), 0, stream>>>(
        q_hi, q_lo, k_hi, k_lo, v_hi, v_lo, o_t);
    // out = Wo @ O + bo
    out_proj<<<dim3(P / 16, 1, BATCH), dim3(64), 0, stream>>>(
        wo_h, wo_l, o_t, bo, out);
}

// Round 4
// 341.217 us; speedup vs baseline: 4.8099x; 1.2681x over previous
//
#include <hip/hip_runtime.h>
#include <math.h>
#include <stdint.h>

// Problem dims (fixed)
#define BATCH 4
#define CQ 256      // x channels
#define P 4096      // query positions (64*64)
#define CC 512      // context channels
#define PC 1024     // kv positions (32*32)
#define HID 512     // HEADS*DIM_HEAD
#define HEADS 8
#define DH 64

// Fold attention scale 1/sqrt(64) * log2(e) into Q so softmax uses exp2.
#define QSCALE 0.180336880111113703f

typedef __attribute__((ext_vector_type(8))) __fp16 f16x8;
typedef __attribute__((ext_vector_type(2))) __fp16 f16x2;
typedef __attribute__((ext_vector_type(4))) float f32x4;
typedef __attribute__((ext_vector_type(4))) unsigned int u32x4;

union H2U { f16x2 h; uint32_t u; };
union F8U { uint32_t u[4]; f16x8 v; };

__device__ __forceinline__ uint32_t pkh(float a, float b) {
    H2U z; z.h = __builtin_amdgcn_cvt_pkrtz(a, b); return z.u;
}
__device__ __forceinline__ f16x2 upk(uint32_t w) { H2U z; z.u = w; return z.h; }
__device__ __forceinline__ void split2(float a, float b, uint32_t& hw, uint32_t& lw) {
    hw = pkh(a, b);
    f16x2 h = upk(hw);
    lw = pkh(a - (float)h[0], b - (float)h[1]);
}

#define MFMA16(a, b, c) __builtin_amdgcn_mfma_f32_16x16x32_f16(a, b, c, 0, 0, 0)

// ---------------------------------------------------------------------------
// fp32 tiled GEMM: C[b] = A (MxK, shared) * B[b] (KxN); epilogue writes
// split fp16 hi/lo. MODE 0: out[b][h][pos][c64] (Q/K); MODE 1: out[b][c][pos].
// ---------------------------------------------------------------------------
template<int MODE>
__global__ __launch_bounds__(256) void gemm_split(
    const float* __restrict__ A, const float* __restrict__ B,
    unsigned short* __restrict__ Dh, unsigned short* __restrict__ Dl,
    float scale, int M, int K, int N)
{
    const int b = blockIdx.z;
    const float* Bb = B + (size_t)b * K * N;
    const int tn = blockIdx.x * 64;
    const int tm = blockIdx.y * 64;
    const int tid = threadIdx.x;
    const int tx = tid & 15, ty = tid >> 4;

    __shared__ float As[16][68];  // [kk][m]
    __shared__ float Bs[16][68];  // [kk][n]

    float acc[4][4] = {};

    for (int k0 = 0; k0 < K; k0 += 16) {
        {
            int m = tid >> 2;
            int kk = (tid & 3) * 4;
            const float4 a4 = *reinterpret_cast<const float4*>(
                &A[(size_t)(tm + m) * K + k0 + kk]);
            As[kk + 0][m] = a4.x; As[kk + 1][m] = a4.y;
            As[kk + 2][m] = a4.z; As[kk + 3][m] = a4.w;
        }
        {
            int kk = tid >> 4;
            int n = (tid & 15) * 4;
            *reinterpret_cast<float4*>(&Bs[kk][n]) =
                *reinterpret_cast<const float4*>(&Bb[(size_t)(k0 + kk) * N + tn + n]);
        }
        __syncthreads();
        #pragma unroll
        for (int kk = 0; kk < 16; ++kk) {
            float4 a = *reinterpret_cast<const float4*>(&As[kk][ty * 4]);
            float4 bv = *reinterpret_cast<const float4*>(&Bs[kk][tx * 4]);
            float av[4] = {a.x, a.y, a.z, a.w};
            float bb[4] = {bv.x, bv.y, bv.z, bv.w};
            #pragma unroll
            for (int i2 = 0; i2 < 4; ++i2)
                #pragma unroll
                for (int j2 = 0; j2 < 4; ++j2)
                    acc[i2][j2] = fmaf(av[i2], bb[j2], acc[i2][j2]);
        }
        __syncthreads();
    }

    if (MODE == 0) {
        const int h = tm >> 6;
        #pragma unroll
        for (int j2 = 0; j2 < 4; ++j2) {
            int pos = tn + tx * 4 + j2;
            uint32_t hw0, hw1, lw0, lw1;
            split2(scale * acc[0][j2], scale * acc[1][j2], hw0, lw0);
            split2(scale * acc[2][j2], scale * acc[3][j2], hw1, lw1);
            size_t off = (((size_t)b * HEADS + h) * (size_t)N + pos) * 64 + ty * 4;
            uint2 hh; hh.x = hw0; hh.y = hw1;
            uint2 ll; ll.x = lw0; ll.y = lw1;
            *reinterpret_cast<uint2*>(Dh + off) = hh;
            *reinterpret_cast<uint2*>(Dl + off) = ll;
        }
    } else {
        #pragma unroll
        for (int i2 = 0; i2 < 4; ++i2) {
            int c = tm + ty * 4 + i2;
            uint32_t hw0, hw1, lw0, lw1;
            split2(acc[i2][0], acc[i2][1], hw0, lw0);
            split2(acc[i2][2], acc[i2][3], hw1, lw1);
            size_t off = ((size_t)b * HID + c) * (size_t)N + tn + tx * 4;
            uint2 hh; hh.x = hw0; hh.y = hw1;
            uint2 ll; ll.x = lw0; ll.y = lw1;
            *reinterpret_cast<uint2*>(Dh + off) = hh;
            *reinterpret_cast<uint2*>(Dl + off) = ll;
        }
    }
}

// ---------------------------------------------------------------------------
// Split Wo into fp16 hi only (2-term output projection).
// ---------------------------------------------------------------------------
__global__ __launch_bounds__(256) void split_w(
    const float* __restrict__ W, unsigned short* __restrict__ Wh, int n)
{
    int i = blockIdx.x * 256 + threadIdx.x;
    if (i < n) Wh[i] = (unsigned short)(pkh(W[i], 0.f) & 0xffffu);
}

// ---------------------------------------------------------------------------
// Flash attention, split-fp16 MFMA. Block = 4 independent waves, each owning
// one 64-query tile. K double-buffered in regs (prefetch 1 half-iter ahead);
// V issued between S-MFMA and softmax. S = 3-term split, PV = 2-term (P hi).
//   q,k: [b][h][pos][64c] fp16 hi/lo   v: [b][c][pos] fp16 hi/lo
//   o: interleaved u32x4 per 4 channels: [h01,h23,l01,l23]
// ---------------------------------------------------------------------------
#define LOADK(DST, JT) do {                                                   \
    const int j0_ = (JT) * 32;                                                \
    _Pragma("unroll")                                                         \
    for (int jm = 0; jm < 2; ++jm) {                                          \
        const size_t krow = kbase + (size_t)(j0_ + 16 * jm + ln) * 64 + 8 * g;\
        _Pragma("unroll")                                                     \
        for (int ks = 0; ks < 2; ++ks) {                                      \
            DST[jm][ks][0] = *reinterpret_cast<const f16x8*>(kh + krow + 32 * ks); \
            DST[jm][ks][1] = *reinterpret_cast<const f16x8*>(kl + krow + 32 * ks); \
        }                                                                     \
    }                                                                         \
} while (0)

#define ATTN_STEP(KC, KN, JT, JTN) do {                                       \
    const int j0 = (JT) * 32;                                                 \
    LOADK(KN, (JTN));                                                         \
    f32x4 s[2][4];                                                            \
    _Pragma("unroll")                                                         \
    for (int jm = 0; jm < 2; ++jm)                                            \
        _Pragma("unroll")                                                     \
        for (int in_ = 0; in_ < 4; ++in_) {                                   \
            f32x4 z = {0.f, 0.f, 0.f, 0.f}; s[jm][in_] = z;                   \
        }                                                                     \
    _Pragma("unroll")                                                         \
    for (int jm = 0; jm < 2; ++jm)                                            \
        _Pragma("unroll")                                                     \
        for (int ks = 0; ks < 2; ++ks)                                        \
            _Pragma("unroll")                                                 \
            for (int in_ = 0; in_ < 4; ++in_) {                               \
                s[jm][in_] = MFMA16(KC[jm][ks][0], qf[in_][ks][0], s[jm][in_]); \
                s[jm][in_] = MFMA16(KC[jm][ks][0], qf[in_][ks][1], s[jm][in_]); \
                s[jm][in_] = MFMA16(KC[jm][ks][1], qf[in_][ks][0], s[jm][in_]); \
            }                                                                 \
    f16x8 vfh[4], vfl[4];                                                     \
    _Pragma("unroll")                                                         \
    for (int cm = 0; cm < 4; ++cm) {                                          \
        const size_t vrow = vbase + (size_t)(16 * cm + ln) * PC + j0 + 8 * g; \
        vfh[cm] = *reinterpret_cast<const f16x8*>(vh + vrow);                 \
        vfl[cm] = *reinterpret_cast<const f16x8*>(vl + vrow);                 \
    }                                                                         \
    uint32_t pw[2][4][2];                                                     \
    _Pragma("unroll")                                                         \
    for (int in_ = 0; in_ < 4; ++in_) {                                       \
        float tmx = fmaxf(fmaxf(fmaxf(s[0][in_][0], s[0][in_][1]),            \
                                fmaxf(s[0][in_][2], s[0][in_][3])),           \
                          fmaxf(fmaxf(s[1][in_][0], s[1][in_][1]),            \
                                fmaxf(s[1][in_][2], s[1][in_][3])));          \
        tmx = fmaxf(tmx, __shfl_xor(tmx, 16, 64));                            \
        tmx = fmaxf(tmx, __shfl_xor(tmx, 32, 64));                            \
        float mnew = fmaxf(mst[in_], tmx);                                    \
        float fac = exp2f(mst[in_] - mnew);                                   \
        float rs = 0.f;                                                       \
        _Pragma("unroll")                                                     \
        for (int jm = 0; jm < 2; ++jm)                                        \
            _Pragma("unroll")                                                 \
            for (int r = 0; r < 4; ++r) {                                     \
                float p = exp2f(s[jm][in_][r] - mnew);                        \
                s[jm][in_][r] = p; rs += p;                                   \
            }                                                                 \
        rs += __shfl_xor(rs, 16, 64);                                         \
        rs += __shfl_xor(rs, 32, 64);                                         \
        lst[in_] = lst[in_] * fac + rs;                                       \
        mst[in_] = mnew;                                                      \
        _Pragma("unroll")                                                     \
        for (int jm = 0; jm < 2; ++jm) {                                      \
            pw[jm][in_][0] = pkh(s[jm][in_][0], s[jm][in_][1]);               \
            pw[jm][in_][1] = pkh(s[jm][in_][2], s[jm][in_][3]);               \
        }                                                                     \
        _Pragma("unroll")                                                     \
        for (int cm = 0; cm < 4; ++cm) acc[cm][in_] *= fac;                   \
    }                                                                         \
    _Pragma("unroll")                                                         \
    for (int in_ = 0; in_ < 4; ++in_) {                                       \
        int w00 = (int)pw[0][in_][0], w01 = (int)pw[0][in_][1];               \
        int w10 = (int)pw[1][in_][0], w11 = (int)pw[1][in_][1];               \
        int a0 = __shfl(w00, idx0, 64), a1 = __shfl(w01, idx0, 64);           \
        int a2 = __shfl(w00, idx1, 64), a3 = __shfl(w01, idx1, 64);           \
        int b0 = __shfl(w10, idx0, 64), b1 = __shfl(w11, idx0, 64);           \
        int b2 = __shfl(w10, idx1, 64), b3 = __shfl(w11, idx1, 64);           \
        F8U fu;                                                               \
        fu.u[0] = (uint32_t)(topTile ? b0 : a0);                              \
        fu.u[1] = (uint32_t)(topTile ? b1 : a1);                              \
        fu.u[2] = (uint32_t)(topTile ? b2 : a2);                              \
        fu.u[3] = (uint32_t)(topTile ? b3 : a3);                              \
        _Pragma("unroll")                                                     \
        for (int cm = 0; cm < 4; ++cm) {                                      \
            acc[cm][in_] = MFMA16(vfh[cm], fu.v, acc[cm][in_]);               \
            acc[cm][in_] = MFMA16(vfl[cm], fu.v, acc[cm][in_]);               \
        }                                                                     \
    }                                                                         \
} while (0)

__global__ __launch_bounds__(256, 2) void attn_mfma(
    const unsigned short* __restrict__ qh, const unsigned short* __restrict__ ql,
    const unsigned short* __restrict__ kh, const unsigned short* __restrict__ kl,
    const unsigned short* __restrict__ vh, const unsigned short* __restrict__ vl,
    uint32_t* __restrict__ ohl)
{
    const int wid = threadIdx.x >> 6;
    const int l = threadIdx.x & 63;
    const int ln = l & 15, g = l >> 4;
    const int i0 = (blockIdx.x * 4 + wid) * 64;
    const int h = blockIdx.y, b = blockIdx.z;

    const size_t qbase = (size_t)(b * HEADS + h) * P * 64;
    const size_t kbase = (size_t)(b * HEADS + h) * PC * 64;
    const size_t vbase = (size_t)(b * HID + h * DH) * PC;

    // Q B-frags: lane holds q[i=i0+16in+ln][c=32ks+8g .. +7], hi/lo
    f16x8 qf[4][2][2];
    #pragma unroll
    for (int in_ = 0; in_ < 4; ++in_) {
        const size_t qrow = qbase + (size_t)(i0 + 16 * in_ + ln) * 64 + 8 * g;
        #pragma unroll
        for (int ks = 0; ks < 2; ++ks) {
            qf[in_][ks][0] = *reinterpret_cast<const f16x8*>(qh + qrow + 32 * ks);
            qf[in_][ks][1] = *reinterpret_cast<const f16x8*>(ql + qrow + 32 * ks);
        }
    }

    f32x4 acc[4][4];  // O^T frags: rows c=16cm+4g+r, col i=16in+ln
    #pragma unroll
    for (int cm = 0; cm < 4; ++cm)
        #pragma unroll
        for (int in_ = 0; in_ < 4; ++in_) {
            f32x4 z = {0.f, 0.f, 0.f, 0.f};
            acc[cm][in_] = z;
        }
    float mst[4], lst[4];
    #pragma unroll
    for (int in_ = 0; in_ < 4; ++in_) { mst[in_] = -1e30f; lst[in_] = 0.f; }

    const int idx0 = ln + 16 * (2 * (g & 1));
    const int idx1 = idx0 + 16;
    const bool topTile = (g & 2) != 0;

    f16x8 kA[2][2][2], kB[2][2][2];
    LOADK(kA, 0);

    for (int jt = 0; jt < 32; jt += 2) {
        ATTN_STEP(kA, kB, jt, jt + 1);
        ATTN_STEP(kB, kA, jt + 1, (jt + 2) & 31);
    }

    // epilogue: O/l -> interleaved fp16 hi/lo
    #pragma unroll
    for (int in_ = 0; in_ < 4; ++in_) {
        float inv = 1.0f / lst[in_];
        int i = i0 + 16 * in_ + ln;
        #pragma unroll
        for (int cm = 0; cm < 4; ++cm) {
            f32x4 o4 = acc[cm][in_] * inv;
            uint32_t h01, h23, l01, l23;
            split2(o4[0], o4[1], h01, l01);
            split2(o4[2], o4[3], h23, l23);
            u32x4 wv; wv[0] = h01; wv[1] = h23; wv[2] = l01; wv[3] = l23;
            size_t idx = ((size_t)b * P + i) * 512 + (size_t)(h * DH + 16 * cm + 4 * g);
            *reinterpret_cast<u32x4*>(ohl + idx) = wv;
        }
    }
}

// ---------------------------------------------------------------------------
// Output projection: out[b][o][i] = Wo[o][:] . O[b][i][:] + bo[o].
// 2-term fp16 MFMA (Wo_h * (O_h + O_l)). Block = 4 waves; wave = 64o x 32i.
// ---------------------------------------------------------------------------
__global__ __launch_bounds__(256, 2) void out_proj(
    const unsigned short* __restrict__ woh, const uint32_t* __restrict__ ohl,
    const float* __restrict__ bo, float* __restrict__ out)
{
    const int wid = threadIdx.x >> 6;
    const int l = threadIdx.x & 63;
    const int ln = l & 15, g = l >> 4;
    const int ibase = blockIdx.x * 128 + wid * 32;
    const int otile = blockIdx.y * 64;
    const int b = blockIdx.z;

    f32x4 acc[4][2];
    #pragma unroll
    for (int mt = 0; mt < 4; ++mt)
        #pragma unroll
        for (int nt = 0; nt < 2; ++nt) {
            f32x4 z = {0.f, 0.f, 0.f, 0.f};
            acc[mt][nt] = z;
        }

    #pragma unroll
    for (int ks = 0; ks < 16; ++ks) {
        const int c0 = 32 * ks + 8 * g;
        f16x8 wf[4];
        #pragma unroll
        for (int mt = 0; mt < 4; ++mt)
            wf[mt] = *reinterpret_cast<const f16x8*>(
                woh + (size_t)(otile + 16 * mt + ln) * HID + c0);
        #pragma unroll
        for (int nt = 0; nt < 2; ++nt) {
            const size_t obase = ((size_t)b * P + ibase + 16 * nt + ln) * 512 + c0;
            u32x4 A = *reinterpret_cast<const u32x4*>(ohl + obase);
            u32x4 Bv = *reinterpret_cast<const u32x4*>(ohl + obase + 4);
            F8U bh, bl;
            bh.u[0] = A[0]; bh.u[1] = A[1]; bh.u[2] = Bv[0]; bh.u[3] = Bv[1];
            bl.u[0] = A[2]; bl.u[1] = A[3]; bl.u[2] = Bv[2]; bl.u[3] = Bv[3];
            #pragma unroll
            for (int mt = 0; mt < 4; ++mt) {
                acc[mt][nt] = MFMA16(wf[mt], bh.v, acc[mt][nt]);
                acc[mt][nt] = MFMA16(wf[mt], bl.v, acc[mt][nt]);
            }
        }
    }

    #pragma unroll
    for (int mt = 0; mt < 4; ++mt)
        #pragma unroll
        for (int r = 0; r < 4; ++r) {
            int o_ = otile + 16 * mt + 4 * g + r;
            float bv = bo[o_];
            #pragma unroll
            for (int nt = 0; nt < 2; ++nt)
                out[((size_t)b * CQ + o_) * P + ibase + 16 * nt + ln] =
                    acc[mt][nt][r] + bv;
        }
}

extern "C" void kernel_launch(void* const* d_in, const int* in_sizes, int n_in,
                              void* d_out, int out_size, void* d_ws, size_t ws_size,
                              hipStream_t stream) {
    (void)in_sizes; (void)n_in; (void)out_size; (void)ws_size;
    const float* x   = (const float*)d_in[0];
    const float* ctx = (const float*)d_in[1];
    const float* Wq  = (const float*)d_in[2];
    const float* Wk  = (const float*)d_in[3];
    const float* Wv  = (const float*)d_in[4];
    const float* Wo  = (const float*)d_in[5];
    const float* bo  = (const float*)d_in[6];
    float* out = (float*)d_out;

    unsigned short* qh = (unsigned short*)d_ws;            // 8388608
    unsigned short* ql = qh + (size_t)8388608;
    unsigned short* kh = ql + (size_t)8388608;             // 2097152
    unsigned short* kl = kh + (size_t)2097152;
    unsigned short* vh = kl + (size_t)2097152;
    unsigned short* vl = vh + (size_t)2097152;
    unsigned short* woh = vl + (size_t)2097152;            // 131072
    uint32_t* ohl = (uint32_t*)(woh + (size_t)2 * 131072); // 8388608 u32, 16B-aligned

    dim3 blk(256);
    split_w<<<dim3(512), blk, 0, stream>>>(Wo, woh, CQ * HID);
    // Q = (QSCALE * Wq) @ x   -> [b][h][4096][64] fp16 hi/lo
    gemm_split<0><<<dim3(P / 64, HID / 64, BATCH), blk, 0, stream>>>(
        Wq, x, qh, ql, QSCALE, HID, CQ, P);
    // K = Wk @ ctx            -> [b][h][1024][64] fp16 hi/lo
    gemm_split<0><<<dim3(PC / 64, HID / 64, BATCH), blk, 0, stream>>>(
        Wk, ctx, kh, kl, 1.0f, HID, CC, PC);
    // V = Wv @ ctx            -> [b][512][1024] fp16 hi/lo
    gemm_split<1><<<dim3(PC / 64, HID / 64, BATCH), blk, 0, stream>>>(
        Wv, ctx, vh, vl, 1.0f, HID, CC, PC);
    // attention -> ohl (fp16 hi/lo interleaved) [b][i][512]
    attn_mfma<<<dim3(P / 256, HEADS, BATCH), blk, 0, stream>>>(
        qh, ql, kh, kl, vh, vl, ohl);
    // out = Wo @ O + bo
    out_proj<<<dim3(P / 128, CQ / 64, BATCH), blk, 0, stream>>>(
        woh, ohl, bo, out);
}